// Round 9
// baseline (31.686 us; speedup 1.0000x reference)
//
#include <hip/hip_runtime.h>

#define NPTS 128
#define FAR_DELTA 1e10f
#define EPS_T 1e-10f
#define GATE 1e-3f   // each skip mechanism discards <= GATE total weight;
                     // 3 mechanisms -> <= 3e-3 added error vs 1.94e-2 threshold

typedef float floatx4 __attribute__((ext_vector_type(4)));  // for nontemporal builtin

__global__ __launch_bounds__(256) void volsdf_render_kernel(
    const float* __restrict__ distance,
    const float* __restrict__ color,
    const float* __restrict__ slen,
    float* __restrict__ out_color,
    float* __restrict__ geometry,
    int nrays)
{
    // One-shot grid: one wave (64 lanes) per ray, 2 chunks of 64 points.
    // All cross-lane ops are the proven __shfl variants -- no DPP.
    const int wave = threadIdx.x >> 6;   // 0..3 within block
    const int lane = threadIdx.x & 63;
    const int r = blockIdx.x * 4 + wave;
    if (r >= nrays) return;

    const size_t base = (size_t)r * NPTS;

    // ---- geometry zeros FIRST: the 96 MB write stream issues with no deps,
    // overlapping everything that follows (it was previously serialized after
    // the scan->load->reduce chain).
    floatx4* g4 = reinterpret_cast<floatx4*>(geometry + base * 3);
    const floatx4 z = {0.f, 0.f, 0.f, 0.f};
    __builtin_nontemporal_store(z, g4 + lane);
    if (lane < 32) __builtin_nontemporal_store(z, g4 + 64 + lane);

    // ---- chunk 0: points 0..63 ----
    float d0  = distance[base + lane];
    float s0  = slen[base + lane];
    float s64 = slen[base + 64];                 // uniform addr -> 1 fetch

    // Speculative ungated color prefetch for lanes 0..31 (nearly always live:
    // trans typically crosses GATE around point ~44) -> overlaps the scan.
    float pc0 = 0.f, pc1 = 0.f, pc2 = 0.f;
    if (lane < 32) {
        const float* cp = color + (base + lane) * 3;
        pc0 = cp[0]; pc1 = cp[1]; pc2 = cp[2];
    }

    float sl_next = __shfl_down(s0, 1, 64);
    float delta0 = (lane == 63) ? (s64 - s0) : (sl_next - s0);

    // density = 10 * sigmoid(-d/0.05) = 10 / (1 + exp(20 d))
    float dens0 = 10.0f / (1.0f + __expf(20.0f * d0));
    float e0 = __expf(-dens0 * delta0);          // (1-alpha+eps) = e+eps
    float t0 = e0 + EPS_T;

    // Inclusive product scan (proven: shuffle outside, guarded multiply)
    float incl0 = t0;
    #pragma unroll
    for (int off = 1; off < 64; off <<= 1) {
        float up = __shfl_up(incl0, off, 64);
        if (lane >= off) incl0 *= up;
    }
    float eup0 = __shfl_up(incl0, 1, 64);
    float excl0 = (lane == 0) ? 1.0f : eup0;
    float w0 = excl0 * (1.0f - e0);

    // Lanes 0..31: use prefetched color. Lanes 32..63: gated-after-scan load
    // (this is where the fetch savings are -- trans is usually dead there).
    float a0 = 0.f, a1 = 0.f, a2 = 0.f;
    if (lane < 32) {
        a0 = w0 * pc0; a1 = w0 * pc1; a2 = w0 * pc2;
    } else if (excl0 >= GATE) {
        const float* cp = color + (base + lane) * 3;
        a0 = w0 * cp[0]; a1 = w0 * cp[1]; a2 = w0 * cp[2];
    }

    // Carry transmittance after 64 points; wave-uniform by construction
    float T0 = __shfl(incl0, 63, 64);

    if (T0 >= GATE) {
        // ---- chunk 1: points 64..127 (~25% of rays reach here) ----
        float d1 = distance[base + 64 + lane];
        float s1 = slen[base + 64 + lane];
        float sn1 = __shfl_down(s1, 1, 64);
        float delta1 = (lane == 63) ? FAR_DELTA : (sn1 - s1);

        float dens1 = 10.0f / (1.0f + __expf(20.0f * d1));
        float e1 = __expf(-dens1 * delta1);
        float t1 = e1 + EPS_T;

        float incl1 = t1;
        #pragma unroll
        for (int off = 1; off < 64; off <<= 1) {
            float up = __shfl_up(incl1, off, 64);
            if (lane >= off) incl1 *= up;
        }
        float eup1 = __shfl_up(incl1, 1, 64);
        float excl1 = ((lane == 0) ? 1.0f : eup1) * T0;   // carry-in

        if (excl1 >= GATE) {                               // per-lane suffix gate
            const float* cp1 = color + (base + 64 + lane) * 3;
            float w1 = excl1 * (1.0f - e1);
            a0 += w1 * cp1[0];
            a1 += w1 * cp1[1];
            a2 += w1 * cp1[2];
        }
    }

    // 3-channel wave tree-reduce (proven); totals land in lane 0
    #pragma unroll
    for (int off = 32; off > 0; off >>= 1) {
        a0 += __shfl_down(a0, off, 64);
        a1 += __shfl_down(a1, off, 64);
        a2 += __shfl_down(a2, off, 64);
    }
    if (lane == 0) {
        float* op = out_color + (size_t)r * 3;
        op[0] = a0; op[1] = a1; op[2] = a2;
    }
}

extern "C" void kernel_launch(void* const* d_in, const int* in_sizes, int n_in,
                              void* d_out, int out_size, void* d_ws, size_t ws_size,
                              hipStream_t stream) {
    const float* distance = (const float*)d_in[0];
    const float* color    = (const float*)d_in[1];
    const float* slen     = (const float*)d_in[2];

    const int R = in_sizes[0] / NPTS;   // 65536
    float* out_color = (float*)d_out;
    float* geometry  = out_color + (size_t)R * 3;

    // One-shot grid: R/4 blocks, one ray per wave. Fresh blocks replenish the
    // CUs as waves retire -> natural cross-ray pipelining, no grid-stride loop.
    int grid = (R + 3) / 4;   // 16384
    hipLaunchKernelGGL(volsdf_render_kernel, dim3(grid), dim3(256), 0, stream,
                       distance, color, slen, out_color, geometry, R);
}

// Round 10
// 29.035 us; speedup vs baseline: 1.0913x; 1.0913x over previous
//
#include <hip/hip_runtime.h>

#define NPTS 128
#define FAR_DELTA 1e10f
#define EPS_T 1e-10f
#define GATE 1e-3f   // each skip mechanism discards <= GATE total weight;
                     // 3 mechanisms -> <= 3e-3 added error vs 1.94e-2 threshold
#define NFILL 1024   // dedicated geometry-fill blocks (every 17th block)

typedef float floatx4 __attribute__((ext_vector_type(4)));  // for nontemporal builtin

__global__ __launch_bounds__(256) void volsdf_render_kernel(
    const float* __restrict__ distance,
    const float* __restrict__ color,
    const float* __restrict__ slen,
    float* __restrict__ out_color,
    float* __restrict__ geometry,
    int nrays)
{
    // Block-level wave specialization:
    //  - every 17th block is a PURE FILL block: 24 independent nt float4
    //    stores/thread (the structure the harness fill kernel runs at ~7 TB/s);
    //  - the rest are RENDER blocks: round-8 path with zero geometry stores,
    //    so their VMEM slots carry only latency-critical loads.
    // Interleaving by blockIdx%17 keeps both streams co-resident on every CU.
    if (blockIdx.x % 17 == 0) {
        const int fid = blockIdx.x / 17;            // 0..NFILL-1
        floatx4* g4 = reinterpret_cast<floatx4*>(geometry);
        const floatx4 z = {0.f, 0.f, 0.f, 0.f};
        const size_t total4 = (size_t)nrays * 96;   // 384 floats/ray / 4
        const size_t per = (total4 + NFILL - 1) / NFILL;   // 6144 for R=65536
        const size_t beg = (size_t)fid * per;
        const size_t end = (beg + per < total4) ? (beg + per) : total4;
        #pragma unroll 4
        for (size_t i = beg + threadIdx.x; i < end; i += 256)
            __builtin_nontemporal_store(z, g4 + i);
        return;
    }

    // ---- render path: identical to round-8 (29.7 us proven) minus stores ----
    const int bid  = blockIdx.x - blockIdx.x / 17 - 1;   // dense render index
    const int wave = threadIdx.x >> 6;   // 0..3 within block
    const int lane = threadIdx.x & 63;
    const int r = bid * 4 + wave;
    if (r >= nrays) return;

    const size_t base = (size_t)r * NPTS;

    // ---- chunk 0: points 0..63 ----
    float d0  = distance[base + lane];
    float s0  = slen[base + lane];
    float s64 = slen[base + 64];                 // uniform addr -> 1 fetch

    float sl_next = __shfl_down(s0, 1, 64);
    float delta0 = (lane == 63) ? (s64 - s0) : (sl_next - s0);

    // density = 10 * sigmoid(-d/0.05) = 10 / (1 + exp(20 d))
    float dens0 = 10.0f / (1.0f + __expf(20.0f * d0));
    float e0 = __expf(-dens0 * delta0);          // (1-alpha+eps) = e+eps
    float t0 = e0 + EPS_T;

    // Inclusive product scan (proven: shuffle outside, guarded multiply)
    float incl0 = t0;
    #pragma unroll
    for (int off = 1; off < 64; off <<= 1) {
        float up = __shfl_up(incl0, off, 64);
        if (lane >= off) incl0 *= up;
    }
    float eup0 = __shfl_up(incl0, 1, 64);
    float excl0 = (lane == 0) ? 1.0f : eup0;
    float w0 = excl0 * (1.0f - e0);

    // Per-lane gated color load: lanes past trans<GATE carry <= GATE total weight
    float a0 = 0.f, a1 = 0.f, a2 = 0.f;
    if (excl0 >= GATE) {
        const float* cp = color + (base + lane) * 3;
        a0 = w0 * cp[0]; a1 = w0 * cp[1]; a2 = w0 * cp[2];
    }

    // Carry transmittance after 64 points; wave-uniform by construction
    float T0 = __shfl(incl0, 63, 64);

    if (T0 >= GATE) {
        // ---- chunk 1: points 64..127 (~25% of rays reach here) ----
        float d1 = distance[base + 64 + lane];
        float s1 = slen[base + 64 + lane];
        float sn1 = __shfl_down(s1, 1, 64);
        float delta1 = (lane == 63) ? FAR_DELTA : (sn1 - s1);

        float dens1 = 10.0f / (1.0f + __expf(20.0f * d1));
        float e1 = __expf(-dens1 * delta1);
        float t1 = e1 + EPS_T;

        float incl1 = t1;
        #pragma unroll
        for (int off = 1; off < 64; off <<= 1) {
            float up = __shfl_up(incl1, off, 64);
            if (lane >= off) incl1 *= up;
        }
        float eup1 = __shfl_up(incl1, 1, 64);
        float excl1 = ((lane == 0) ? 1.0f : eup1) * T0;   // carry-in

        if (excl1 >= GATE) {                               // per-lane suffix gate
            const float* cp1 = color + (base + 64 + lane) * 3;
            float w1 = excl1 * (1.0f - e1);
            a0 += w1 * cp1[0];
            a1 += w1 * cp1[1];
            a2 += w1 * cp1[2];
        }
    }

    // 3-channel wave tree-reduce (proven); totals land in lane 0
    #pragma unroll
    for (int off = 32; off > 0; off >>= 1) {
        a0 += __shfl_down(a0, off, 64);
        a1 += __shfl_down(a1, off, 64);
        a2 += __shfl_down(a2, off, 64);
    }
    if (lane == 0) {
        float* op = out_color + (size_t)r * 3;
        op[0] = a0; op[1] = a1; op[2] = a2;
    }
}

extern "C" void kernel_launch(void* const* d_in, const int* in_sizes, int n_in,
                              void* d_out, int out_size, void* d_ws, size_t ws_size,
                              hipStream_t stream) {
    const float* distance = (const float*)d_in[0];
    const float* color    = (const float*)d_in[1];
    const float* slen     = (const float*)d_in[2];

    const int R = in_sizes[0] / NPTS;   // 65536
    float* out_color = (float*)d_out;
    float* geometry  = out_color + (size_t)R * 3;

    // Grid: 16384 render blocks (4 rays each) + 1024 fill blocks interleaved
    // at every 17th slot -> 17408 blocks total. For general R:
    int render_blocks = (R + 3) / 4;
    // need G - ceil(G/17) >= render_blocks and ceil(G/17) == NFILL when exact;
    // for R=65536: G = 17408 gives exactly 1024 fill + 16384 render.
    int grid = render_blocks + (render_blocks + 15) / 16;
    hipLaunchKernelGGL(volsdf_render_kernel, dim3(grid), dim3(256), 0, stream,
                       distance, color, slen, out_color, geometry, R);
}

// Round 11
// 27.565 us; speedup vs baseline: 1.1495x; 1.0534x over previous
//
#include <hip/hip_runtime.h>

#define NPTS 128
#define FAR_DELTA 1e10f
#define EPS_T 1e-10f
#define GATE 1e-3f   // each skip mechanism discards <= GATE total weight;
                     // 3 mechanisms -> <= 3e-3 added error vs 1.94e-2 threshold
#define NFILL 1024   // dedicated geometry-fill blocks (every 17th block)

typedef float floatx4 __attribute__((ext_vector_type(4)));  // for nontemporal builtin

// --- DPP wave-sum (VALU pipe; proven in round 4) -----------------------------
// row_shr:N = 0x110+N, row_bcast15 = 0x142 (rmask 0xa), row_bcast31 = 0x143
// (rmask 0xc). update_dpp old=0 supplies the add identity on masked lanes.
template <int CTRL, int RMASK>
__device__ __forceinline__ float dpp_add_step(float x) {
    int y = __builtin_amdgcn_update_dpp(0, __float_as_int(x),
                                        CTRL, RMASK, 0xf, false);
    return x + __int_as_float(y);
}

// Sum over 64 lanes; full total lands in lane 63
__device__ __forceinline__ float wave_sum_to_lane63(float s) {
    s = dpp_add_step<0x111, 0xf>(s);
    s = dpp_add_step<0x112, 0xf>(s);
    s = dpp_add_step<0x114, 0xf>(s);
    s = dpp_add_step<0x118, 0xf>(s);
    s = dpp_add_step<0x142, 0xa>(s);
    s = dpp_add_step<0x143, 0xc>(s);
    return s;
}

__global__ __launch_bounds__(256) void volsdf_render_kernel(
    const float* __restrict__ distance,
    const float* __restrict__ color,
    const float* __restrict__ slen,
    float* __restrict__ out_color,
    float* __restrict__ geometry,
    int nrays)
{
    // Block-level wave specialization (round-10-proven):
    //  - every 17th block: pure fill block, 24 independent nt float4 stores/thr
    //  - rest: render blocks, zero geometry stores in their VMEM stream.
    if (blockIdx.x % 17 == 0) {
        const int fid = blockIdx.x / 17;            // 0..NFILL-1
        floatx4* g4 = reinterpret_cast<floatx4*>(geometry);
        const floatx4 z = {0.f, 0.f, 0.f, 0.f};
        const size_t total4 = (size_t)nrays * 96;   // 384 floats/ray / 4
        const size_t per = (total4 + NFILL - 1) / NFILL;   // 6144 for R=65536
        const size_t beg = (size_t)fid * per;
        const size_t end = (beg + per < total4) ? (beg + per) : total4;
        #pragma unroll 4
        for (size_t i = beg + threadIdx.x; i < end; i += 256)
            __builtin_nontemporal_store(z, g4 + i);
        return;
    }

    // ---- render path: round-10-proven; ONLY the epilogue reduce changed ----
    const int bid  = blockIdx.x - blockIdx.x / 17 - 1;   // dense render index
    const int wave = threadIdx.x >> 6;   // 0..3 within block
    const int lane = threadIdx.x & 63;
    const int r = bid * 4 + wave;
    if (r >= nrays) return;

    const size_t base = (size_t)r * NPTS;

    // ---- chunk 0: points 0..63 ----
    float d0  = distance[base + lane];
    float s0  = slen[base + lane];
    float s64 = slen[base + 64];                 // uniform addr -> 1 fetch

    float sl_next = __shfl_down(s0, 1, 64);
    float delta0 = (lane == 63) ? (s64 - s0) : (sl_next - s0);

    // density = 10 * sigmoid(-d/0.05) = 10 / (1 + exp(20 d))
    float dens0 = 10.0f / (1.0f + __expf(20.0f * d0));
    float e0 = __expf(-dens0 * delta0);          // (1-alpha+eps) = e+eps
    float t0 = e0 + EPS_T;

    // Inclusive product scan (proven: shuffle outside, guarded multiply)
    float incl0 = t0;
    #pragma unroll
    for (int off = 1; off < 64; off <<= 1) {
        float up = __shfl_up(incl0, off, 64);
        if (lane >= off) incl0 *= up;
    }
    float eup0 = __shfl_up(incl0, 1, 64);
    float excl0 = (lane == 0) ? 1.0f : eup0;
    float w0 = excl0 * (1.0f - e0);

    // Per-lane gated color load: lanes past trans<GATE carry <= GATE total weight
    float a0 = 0.f, a1 = 0.f, a2 = 0.f;
    if (excl0 >= GATE) {
        const float* cp = color + (base + lane) * 3;
        a0 = w0 * cp[0]; a1 = w0 * cp[1]; a2 = w0 * cp[2];
    }

    // Carry transmittance after 64 points; wave-uniform by construction
    float T0 = __shfl(incl0, 63, 64);

    if (T0 >= GATE) {
        // ---- chunk 1: points 64..127 (~25% of rays reach here) ----
        float d1 = distance[base + 64 + lane];
        float s1 = slen[base + 64 + lane];
        float sn1 = __shfl_down(s1, 1, 64);
        float delta1 = (lane == 63) ? FAR_DELTA : (sn1 - s1);

        float dens1 = 10.0f / (1.0f + __expf(20.0f * d1));
        float e1 = __expf(-dens1 * delta1);
        float t1 = e1 + EPS_T;

        float incl1 = t1;
        #pragma unroll
        for (int off = 1; off < 64; off <<= 1) {
            float up = __shfl_up(incl1, off, 64);
            if (lane >= off) incl1 *= up;
        }
        float eup1 = __shfl_up(incl1, 1, 64);
        float excl1 = ((lane == 0) ? 1.0f : eup1) * T0;   // carry-in

        if (excl1 >= GATE) {                               // per-lane suffix gate
            const float* cp1 = color + (base + 64 + lane) * 3;
            float w1 = excl1 * (1.0f - e1);
            a0 += w1 * cp1[0];
            a1 += w1 * cp1[1];
            a2 += w1 * cp1[2];
        }
    }

    // 3-channel wave sum on the VALU pipe (DPP); totals land in lane 63.
    // This replaces 18 ds_bpermute ops + a ~720-cycle dependent DS tail.
    a0 = wave_sum_to_lane63(a0);
    a1 = wave_sum_to_lane63(a1);
    a2 = wave_sum_to_lane63(a2);
    if (lane == 63) {
        float* op = out_color + (size_t)r * 3;
        op[0] = a0; op[1] = a1; op[2] = a2;
    }
}

extern "C" void kernel_launch(void* const* d_in, const int* in_sizes, int n_in,
                              void* d_out, int out_size, void* d_ws, size_t ws_size,
                              hipStream_t stream) {
    const float* distance = (const float*)d_in[0];
    const float* color    = (const float*)d_in[1];
    const float* slen     = (const float*)d_in[2];

    const int R = in_sizes[0] / NPTS;   // 65536
    float* out_color = (float*)d_out;
    float* geometry  = out_color + (size_t)R * 3;

    // 16384 render blocks (4 rays each) + 1024 fill blocks at every 17th slot.
    int render_blocks = (R + 3) / 4;
    int grid = render_blocks + (render_blocks + 15) / 16;   // 17408 for R=65536
    hipLaunchKernelGGL(volsdf_render_kernel, dim3(grid), dim3(256), 0, stream,
                       distance, color, slen, out_color, geometry, R);
}